// Round 1
// baseline (27012.573 us; speedup 1.0000x reference)
//
#include <hip/hip_runtime.h>

#define NN 100000
#define DF 64
#define NE 3200000
#define ALPHA 0.1f
#define BETA 0.9f
#define K_STEPS 10

// out[i] = alpha * x[i], vectorized float4
__global__ void init_h(const float4* __restrict__ x, float4* __restrict__ out, int n4) {
    int i = blockIdx.x * blockDim.x + threadIdx.x;
    if (i < n4) {
        float4 v = x[i];
        v.x *= ALPHA; v.y *= ALPHA; v.z *= ALPHA; v.w *= ALPHA;
        out[i] = v;
    }
}

// 16 lanes per edge; lane handles 4 contiguous features.
// hn[row] += 0.9 * w * h[col]  (feature-wise), via f32 atomics.
__global__ void scatter_edges(const int* __restrict__ row,
                              const int* __restrict__ col,
                              const float* __restrict__ w,
                              const float* __restrict__ h,
                              float* __restrict__ hn) {
    int t = blockIdx.x * blockDim.x + threadIdx.x;
    int e = t >> 4;            // edge index (16 lanes per edge)
    int sub = (t & 15) * 4;    // feature sub-offset 0,4,...,60
    if (e < NE) {
        int c = col[e];
        int r = row[e];
        float wt = BETA * w[e];
        const float4 hv = *(const float4*)(h + (long)c * DF + sub);
        float* dst = hn + (long)r * DF + sub;
        atomicAdd(dst + 0, wt * hv.x);
        atomicAdd(dst + 1, wt * hv.y);
        atomicAdd(dst + 2, wt * hv.z);
        atomicAdd(dst + 3, wt * hv.w);
    }
}

extern "C" void kernel_launch(void* const* d_in, const int* in_sizes, int n_in,
                              void* d_out, int out_size, void* d_ws, size_t ws_size,
                              hipStream_t stream) {
    const float* x    = (const float*)d_in[0];
    const int*   erow = (const int*)  d_in[1];
    const int*   ecol = (const int*)  d_in[2];
    const float* ew   = (const float*)d_in[3];
    float* out = (float*)d_out;
    float* ws  = (float*)d_ws;   // needs 25.6 MB for one [NN, DF] f32 buffer

    const int n  = NN * DF;      // 6.4M
    const int n4 = n / 4;
    dim3 blk(256);
    dim3 gInit((n4 + 255) / 256);
    dim3 gSc(((long)NE * 16 + 255) / 256);   // 200000 blocks

    const float* hcur = x;
    for (int k = 0; k < K_STEPS; ++k) {
        float* tgt = (k & 1) ? out : ws;     // k=9 (last) -> d_out
        init_h<<<gInit, blk, 0, stream>>>((const float4*)x, (float4*)tgt, n4);
        scatter_edges<<<gSc, blk, 0, stream>>>(erow, ecol, ew, hcur, tgt);
        hcur = tgt;
    }
}

// Round 2
// 1774.882 us; speedup vs baseline: 15.2194x; 15.2194x over previous
//
#include <hip/hip_runtime.h>

#define NN 100000
#define NE 3200000
#define DF 64
#define ALPHA 0.1f
#define BETA 0.9f
#define K_STEPS 10
#define SCAN_B 1024
#define NB_SCAN ((NN + SCAN_B - 1) / SCAN_B)   // 98

// ---- CSR build ----------------------------------------------------------

__global__ void hist_rows(const int* __restrict__ row, int* __restrict__ cnt) {
    int e = blockIdx.x * blockDim.x + threadIdx.x;
    if (e < NE) atomicAdd(&cnt[row[e]], 1);
}

// per-block exclusive scan (Hillis-Steele in LDS), emits block totals
__global__ void scan_blocks(const int* __restrict__ cnt, int* __restrict__ rp,
                            int* __restrict__ bsum) {
    __shared__ int s[SCAN_B];
    int i = blockIdx.x * SCAN_B + threadIdx.x;
    int v = (i < NN) ? cnt[i] : 0;
    s[threadIdx.x] = v;
    __syncthreads();
    for (int off = 1; off < SCAN_B; off <<= 1) {
        int t = (threadIdx.x >= off) ? s[threadIdx.x - off] : 0;
        __syncthreads();
        s[threadIdx.x] += t;
        __syncthreads();
    }
    if (i < NN) rp[i] = s[threadIdx.x] - v;          // exclusive
    if (threadIdx.x == SCAN_B - 1) bsum[blockIdx.x] = s[SCAN_B - 1];
}

__global__ void scan_sums(int* __restrict__ bsum) {
    if (blockIdx.x == 0 && threadIdx.x == 0) {
        int run = 0;
        for (int b = 0; b < NB_SCAN; ++b) { int v = bsum[b]; bsum[b] = run; run += v; }
    }
}

__global__ void add_offsets(int* __restrict__ rp, const int* __restrict__ bsum) {
    int i = blockIdx.x * SCAN_B + threadIdx.x;
    if (i < NN) rp[i] += bsum[blockIdx.x];
}

// fill sorted (col, w_bits); mutates rp so that afterwards rp[r] = end of row r
__global__ void fill_csr(const int* __restrict__ row, const int* __restrict__ col,
                         const float* __restrict__ w, int* __restrict__ rp,
                         int2* __restrict__ edges) {
    int e = blockIdx.x * blockDim.x + threadIdx.x;
    if (e < NE) {
        int r = row[e];
        int pos = atomicAdd(&rp[r], 1);
        edges[pos] = make_int2(col[e], __float_as_int(w[e]));
    }
}

// ---- propagation step: pull-mode SpMM, 16 threads per node --------------
// hn[r] = BETA * sum_e w[e]*h[col[e]] + ALPHA * x[r]
__global__ void gather_step(const int* __restrict__ rp, const int2* __restrict__ edges,
                            const float* __restrict__ h, const float* __restrict__ x,
                            float* __restrict__ hn) {
    int t = blockIdx.x * blockDim.x + threadIdx.x;
    int node = t >> 4;
    int q = (t & 15) * 4;                 // feature sub-offset
    if (node >= NN) return;
    int start = (node == 0) ? 0 : rp[node - 1];
    int end = rp[node];
    float4 acc = make_float4(0.f, 0.f, 0.f, 0.f);
    for (int e = start; e < end; ++e) {
        int2 cw = edges[e];
        float wv = __int_as_float(cw.y);
        const float4 hv = *(const float4*)(h + (size_t)cw.x * DF + q);
        acc.x += wv * hv.x; acc.y += wv * hv.y;
        acc.z += wv * hv.z; acc.w += wv * hv.w;
    }
    const float4 xv = *(const float4*)(x + (size_t)node * DF + q);
    float4 o;
    o.x = BETA * acc.x + ALPHA * xv.x;
    o.y = BETA * acc.y + ALPHA * xv.y;
    o.z = BETA * acc.z + ALPHA * xv.z;
    o.w = BETA * acc.w + ALPHA * xv.w;
    *(float4*)(hn + (size_t)node * DF + q) = o;
}

// ---- launch -------------------------------------------------------------

extern "C" void kernel_launch(void* const* d_in, const int* in_sizes, int n_in,
                              void* d_out, int out_size, void* d_ws, size_t ws_size,
                              hipStream_t stream) {
    const float* x    = (const float*)d_in[0];
    const int*   erow = (const int*)  d_in[1];
    const int*   ecol = (const int*)  d_in[2];
    const float* ew   = (const float*)d_in[3];
    float* out = (float*)d_out;

    char* ws = (char*)d_ws;
    float* hbuf  = (float*)(ws);                         // 25,600,000 B
    int*   cnt   = (int*)  (ws + 25600000);              //    400,000 B
    int*   rp    = (int*)  (ws + 26000000);              //    400,000 B
    int2*  edges = (int2*) (ws + 26400000);              // 25,600,000 B
    int*   bsum  = (int*)  (ws + 52000000);              //        512 B

    dim3 blk(256);
    dim3 gE((NE + 255) / 256);                 // 12500 blocks
    dim3 gScan(NB_SCAN);
    dim3 gGather((NN * 16 + 255) / 256);       // 6250 blocks

    // CSR build
    hipMemsetAsync(cnt, 0, NN * sizeof(int), stream);
    hist_rows<<<gE, blk, 0, stream>>>(erow, cnt);
    scan_blocks<<<gScan, SCAN_B, 0, stream>>>(cnt, rp, bsum);
    scan_sums<<<1, 64, 0, stream>>>(bsum);
    add_offsets<<<gScan, SCAN_B, 0, stream>>>(rp, bsum);
    fill_csr<<<gE, blk, 0, stream>>>(erow, ecol, ew, rp, edges);

    // K propagation steps, ping-pong hbuf <-> out, last lands in out
    const float* hcur = x;
    for (int k = 0; k < K_STEPS; ++k) {
        float* tgt = (k & 1) ? out : hbuf;     // k=9 -> out
        gather_step<<<gGather, blk, 0, stream>>>(rp, edges, hcur, x, tgt);
        hcur = tgt;
    }
}